// Round 5
// baseline (102.942 us; speedup 1.0000x reference)
//
#include <hip/hip_runtime.h>
#include <hip/hip_fp16.h>

#define N_HEAD 4
#define F_IN   32
#define F_OUT  32
#define DEG    16

union H4 { ushort4 u; __half h[4]; };
union H8 { uint4 u; __half h[8]; };

__device__ __forceinline__ float4 fma4(float a, float4 x, float4 acc) {
    acc.x = fmaf(a, x.x, acc.x);
    acc.y = fmaf(a, x.y, acc.y);
    acc.z = fmaf(a, x.z, acc.z);
    acc.w = fmaf(a, x.w, acc.w);
    return acc;
}

// Kernel 1: hp[n][h][o] fp16 + a_src/a_dst fp32.
// XCD-swizzled (same chunking as gat_agg) so the hp/adst rows for a node
// chunk are produced — and stay dirty — in the SAME XCD's L2 that consumes
// them in gat_agg. Grid is padded to 8*chunk; OOB guarded.
__global__ __launch_bounds__(256) void gat_proj(
    const float* __restrict__ h, const float* __restrict__ w,
    const float* __restrict__ fc_w,
    ushort4* __restrict__ hp, float* __restrict__ asrc, float* __restrict__ adst,
    int N)
{
    __shared__ float4 wlds[N_HEAD * F_IN * F_OUT / 4];   // 16 KB
    int t = threadIdx.x;
    const float4* w4g = (const float4*)w;
    wlds[t]       = w4g[t];
    wlds[t + 256] = w4g[t + 256];
    wlds[t + 512] = w4g[t + 512];
    wlds[t + 768] = w4g[t + 768];
    __syncthreads();

    int chunk = gridDim.x >> 3;                 // grid = 8*chunk exactly
    int b  = blockIdx.x;
    int vb = (b & 7) * chunk + (b >> 3);        // XCD-contiguous node chunks

    int wid  = t >> 6;
    int lane = t & 63;
    int p    = lane >> 5;
    int sub  = lane & 31;
    int hh   = sub >> 3;
    int q    = sub & 7;
    int node0 = vb * 32;
    int base  = node0 + wid * 8 + p * 4;
    bool full = (node0 + 32 <= N);

    float4 acc[4];
    #pragma unroll
    for (int m = 0; m < 4; ++m) acc[m] = make_float4(0.f, 0.f, 0.f, 0.f);

    const float4* h4 = (const float4*)h;
    if (full) {
        #pragma unroll
        for (int c = 0; c < 8; ++c) {
            float4 wv0 = wlds[hh * 256 + (4 * c + 0) * 8 + q];
            float4 wv1 = wlds[hh * 256 + (4 * c + 1) * 8 + q];
            float4 wv2 = wlds[hh * 256 + (4 * c + 2) * 8 + q];
            float4 wv3 = wlds[hh * 256 + (4 * c + 3) * 8 + q];
            #pragma unroll
            for (int m = 0; m < 4; ++m) {
                float4 hv = h4[(base + m) * 8 + c];
                acc[m] = fma4(hv.x, wv0, acc[m]);
                acc[m] = fma4(hv.y, wv1, acc[m]);
                acc[m] = fma4(hv.z, wv2, acc[m]);
                acc[m] = fma4(hv.w, wv3, acc[m]);
            }
        }
    } else {
        #pragma unroll
        for (int c = 0; c < 8; ++c) {
            float4 wv0 = wlds[hh * 256 + (4 * c + 0) * 8 + q];
            float4 wv1 = wlds[hh * 256 + (4 * c + 1) * 8 + q];
            float4 wv2 = wlds[hh * 256 + (4 * c + 2) * 8 + q];
            float4 wv3 = wlds[hh * 256 + (4 * c + 3) * 8 + q];
            #pragma unroll
            for (int m = 0; m < 4; ++m) {
                int node = base + m;
                int nc   = node < N ? node : N - 1;
                float4 hv = h4[nc * 8 + c];
                acc[m] = fma4(hv.x, wv0, acc[m]);
                acc[m] = fma4(hv.y, wv1, acc[m]);
                acc[m] = fma4(hv.z, wv2, acc[m]);
                acc[m] = fma4(hv.w, wv3, acc[m]);
            }
        }
    }

    float4 fs4 = ((const float4*)fc_w)[q];
    float4 fd4 = ((const float4*)fc_w)[8 + q];
    float ps[4], pd[4];
    #pragma unroll
    for (int m = 0; m < 4; ++m) {
        ps[m] = acc[m].x * fs4.x + acc[m].y * fs4.y + acc[m].z * fs4.z + acc[m].w * fs4.w;
        pd[m] = acc[m].x * fd4.x + acc[m].y * fd4.y + acc[m].z * fd4.z + acc[m].w * fd4.w;
    }
    #pragma unroll
    for (int msk = 1; msk <= 4; msk <<= 1) {
        #pragma unroll
        for (int m = 0; m < 4; ++m) {
            ps[m] += __shfl_xor(ps[m], msk, 64);
            pd[m] += __shfl_xor(pd[m], msk, 64);
        }
    }

    #pragma unroll
    for (int m = 0; m < 4; ++m) {
        int node = base + m;
        if (full || node < N) {
            H4 pk;
            pk.h[0] = __float2half_rn(acc[m].x);
            pk.h[1] = __float2half_rn(acc[m].y);
            pk.h[2] = __float2half_rn(acc[m].z);
            pk.h[3] = __float2half_rn(acc[m].w);
            hp[node * 32 + hh * 8 + q] = pk.u;
            if (q == 0) {
                asrc[node * N_HEAD + hh] = ps[m];
                adst[node * N_HEAD + hh] = pd[m];
            }
        }
    }
}

// Kernel 2: 4 nodes per wave, lane = g*16 + r; r is both the softmax-head
// owner (c=r>>2) and the hp-row slice owner. Same XCD chunking as gat_proj
// so gathers hit the local XCD's L2 (hp chunk = 1.6 MB < 4 MB L2).
__global__ __launch_bounds__(256) void gat_agg(
    const int* __restrict__ dst, const uint4* __restrict__ hp,
    const float* __restrict__ asrc, const float* __restrict__ adst,
    const float* __restrict__ fc_b, const float* __restrict__ bias,
    float* __restrict__ out, int N)
{
    int chunk = gridDim.x >> 3;                 // grid = 8*chunk exactly
    int b  = blockIdx.x;
    int vb = (b & 7) * chunk + (b >> 3);
    int t = threadIdx.x;
    int wid = t >> 6, lane = t & 63;
    int g = lane >> 4, r = lane & 15;
    int node  = vb * 16 + wid * 4 + g;
    int nodec = node < N ? node : N - 1;
    int c = r >> 2;

    // 16 dst indices via 4 int4 loads (uniform within 16-lane group)
    const int4* dst4 = (const int4*)dst;
    int4 d0 = dst4[nodec * 4 + 0];
    int4 d1 = dst4[nodec * 4 + 1];
    int4 d2 = dst4[nodec * 4 + 2];
    int4 d3 = dst4[nodec * 4 + 3];
    int dk[16] = { d0.x, d0.y, d0.z, d0.w, d1.x, d1.y, d1.z, d1.w,
                   d2.x, d2.y, d2.z, d2.w, d3.x, d3.y, d3.z, d3.w };

    float as = asrc[(nodec << 2) + c];
    float bb = fc_b[0];

    // softmax over the 16 edges for head c (in-register, 32-bit addressing)
    float p[16];
    float mx = -1e30f;
    #pragma unroll
    for (int k = 0; k < 16; ++k) {
        float v = as + adst[(dk[k] << 2) + c] + bb;
        v = v > 0.f ? v : 0.2f * v;
        p[k] = v;
        mx = fmaxf(mx, v);
    }
    float s = 0.f;
    #pragma unroll
    for (int k = 0; k < 16; ++k) { p[k] = __expf(p[k] - mx); s += p[k]; }
    float inv = 1.f / s;

    // accumulate slice r over all 16 edges (unnormalized, scale once)
    float acc[8];
    #pragma unroll
    for (int j = 0; j < 8; ++j) acc[j] = 0.f;
    #pragma unroll
    for (int k = 0; k < 16; ++k) {
        H8 v; v.u = hp[(dk[k] << 4) + r];
        float a = p[k];
        #pragma unroll
        for (int j = 0; j < 8; ++j) acc[j] = fmaf(a, __half2float(v.h[j]), acc[j]);
    }
    #pragma unroll
    for (int j = 0; j < 8; ++j) acc[j] *= inv;

    // head-mean: reduce across lanes differing in bits 2,3 of r
    #pragma unroll
    for (int j = 0; j < 8; ++j) acc[j] += __shfl_xor(acc[j], 4, 64);
    #pragma unroll
    for (int j = 0; j < 8; ++j) acc[j] += __shfl_xor(acc[j], 8, 64);

    if (node < N && r < 4) {
        float4 b0 = ((const float4*)bias)[r * 2];
        float4 b1 = ((const float4*)bias)[r * 2 + 1];
        float4 o0, o1;
        o0.x = 0.25f * acc[0] + b0.x;
        o0.y = 0.25f * acc[1] + b0.y;
        o0.z = 0.25f * acc[2] + b0.z;
        o0.w = 0.25f * acc[3] + b0.w;
        o1.x = 0.25f * acc[4] + b1.x;
        o1.y = 0.25f * acc[5] + b1.y;
        o1.z = 0.25f * acc[6] + b1.z;
        o1.w = 0.25f * acc[7] + b1.w;
        ((float4*)out)[node * 8 + r * 2]     = o0;
        ((float4*)out)[node * 8 + r * 2 + 1] = o1;
    }
}

extern "C" void kernel_launch(void* const* d_in, const int* in_sizes, int n_in,
                              void* d_out, int out_size, void* d_ws, size_t ws_size,
                              hipStream_t stream) {
    const float* h    = (const float*)d_in[0];
    const int*   eidx = (const int*)  d_in[1];
    const float* w    = (const float*)d_in[2];
    const float* fc_w = (const float*)d_in[3];
    const float* fc_b = (const float*)d_in[4];
    const float* bias = (const float*)d_in[5];

    int N = in_sizes[0] / F_IN;
    int E = in_sizes[1] / 2;
    const int* dst = eidx + E;     // edge_index[1]

    ushort4* hp  = (ushort4*)d_ws;                     // N*32 ushort4 (fp16)
    float* asrc  = (float*)(hp + (size_t)N * 32);      // N*4
    float* adst  = asrc + (size_t)N * N_HEAD;          // N*4
    float* out   = (float*)d_out;

    // proj: 32 nodes/block, XCD-chunked grid padded to 8*chunk
    int nbp    = (N + 31) / 32;
    int chunkp = (nbp + 7) / 8;
    gat_proj<<<8 * chunkp, 256, 0, stream>>>(h, w, fc_w, hp, asrc, adst, N);

    // agg: 16 nodes/block, identical chunking
    int nvb    = (N + 15) / 16;
    int chunka = (nvb + 7) / 8;
    gat_agg<<<8 * chunka, 256, 0, stream>>>(dst, (const uint4*)hp, asrc, adst,
                                            fc_b, bias, out, N);
}

// Round 6
// 100.754 us; speedup vs baseline: 1.0217x; 1.0217x over previous
//
#include <hip/hip_runtime.h>
#include <hip/hip_fp16.h>

#define N_HEAD 4
#define F_IN   32
#define F_OUT  32
#define DEG    16

union H4 { ushort4 u; __half h[4]; };
union H8 { uint4 u; __half h[8]; };

__device__ __forceinline__ float4 fma4(float a, float4 x, float4 acc) {
    acc.x = fmaf(a, x.x, acc.x);
    acc.y = fmaf(a, x.y, acc.y);
    acc.z = fmaf(a, x.z, acc.z);
    acc.w = fmaf(a, x.w, acc.w);
    return acc;
}

// Kernel 1 (unchanged from R5): hp[n][h][o] fp16 + a_src/a_dst fp32, XCD-chunked.
__global__ __launch_bounds__(256) void gat_proj(
    const float* __restrict__ h, const float* __restrict__ w,
    const float* __restrict__ fc_w,
    ushort4* __restrict__ hp, float* __restrict__ asrc, float* __restrict__ adst,
    int N)
{
    __shared__ float4 wlds[N_HEAD * F_IN * F_OUT / 4];   // 16 KB
    int t = threadIdx.x;
    const float4* w4g = (const float4*)w;
    wlds[t]       = w4g[t];
    wlds[t + 256] = w4g[t + 256];
    wlds[t + 512] = w4g[t + 512];
    wlds[t + 768] = w4g[t + 768];
    __syncthreads();

    int chunk = gridDim.x >> 3;
    int b  = blockIdx.x;
    int vb = (b & 7) * chunk + (b >> 3);

    int wid  = t >> 6;
    int lane = t & 63;
    int p    = lane >> 5;
    int sub  = lane & 31;
    int hh   = sub >> 3;
    int q    = sub & 7;
    int node0 = vb * 32;
    int base  = node0 + wid * 8 + p * 4;
    bool full = (node0 + 32 <= N);

    float4 acc[4];
    #pragma unroll
    for (int m = 0; m < 4; ++m) acc[m] = make_float4(0.f, 0.f, 0.f, 0.f);

    const float4* h4 = (const float4*)h;
    if (full) {
        #pragma unroll
        for (int c = 0; c < 8; ++c) {
            float4 wv0 = wlds[hh * 256 + (4 * c + 0) * 8 + q];
            float4 wv1 = wlds[hh * 256 + (4 * c + 1) * 8 + q];
            float4 wv2 = wlds[hh * 256 + (4 * c + 2) * 8 + q];
            float4 wv3 = wlds[hh * 256 + (4 * c + 3) * 8 + q];
            #pragma unroll
            for (int m = 0; m < 4; ++m) {
                float4 hv = h4[(base + m) * 8 + c];
                acc[m] = fma4(hv.x, wv0, acc[m]);
                acc[m] = fma4(hv.y, wv1, acc[m]);
                acc[m] = fma4(hv.z, wv2, acc[m]);
                acc[m] = fma4(hv.w, wv3, acc[m]);
            }
        }
    } else {
        #pragma unroll
        for (int c = 0; c < 8; ++c) {
            float4 wv0 = wlds[hh * 256 + (4 * c + 0) * 8 + q];
            float4 wv1 = wlds[hh * 256 + (4 * c + 1) * 8 + q];
            float4 wv2 = wlds[hh * 256 + (4 * c + 2) * 8 + q];
            float4 wv3 = wlds[hh * 256 + (4 * c + 3) * 8 + q];
            #pragma unroll
            for (int m = 0; m < 4; ++m) {
                int node = base + m;
                int nc   = node < N ? node : N - 1;
                float4 hv = h4[nc * 8 + c];
                acc[m] = fma4(hv.x, wv0, acc[m]);
                acc[m] = fma4(hv.y, wv1, acc[m]);
                acc[m] = fma4(hv.z, wv2, acc[m]);
                acc[m] = fma4(hv.w, wv3, acc[m]);
            }
        }
    }

    float4 fs4 = ((const float4*)fc_w)[q];
    float4 fd4 = ((const float4*)fc_w)[8 + q];
    float ps[4], pd[4];
    #pragma unroll
    for (int m = 0; m < 4; ++m) {
        ps[m] = acc[m].x * fs4.x + acc[m].y * fs4.y + acc[m].z * fs4.z + acc[m].w * fs4.w;
        pd[m] = acc[m].x * fd4.x + acc[m].y * fd4.y + acc[m].z * fd4.z + acc[m].w * fd4.w;
    }
    #pragma unroll
    for (int msk = 1; msk <= 4; msk <<= 1) {
        #pragma unroll
        for (int m = 0; m < 4; ++m) {
            ps[m] += __shfl_xor(ps[m], msk, 64);
            pd[m] += __shfl_xor(pd[m], msk, 64);
        }
    }

    #pragma unroll
    for (int m = 0; m < 4; ++m) {
        int node = base + m;
        if (full || node < N) {
            H4 pk;
            pk.h[0] = __float2half_rn(acc[m].x);
            pk.h[1] = __float2half_rn(acc[m].y);
            pk.h[2] = __float2half_rn(acc[m].z);
            pk.h[3] = __float2half_rn(acc[m].w);
            hp[node * 32 + hh * 8 + q] = pk.u;
            if (q == 0) {
                asrc[node * N_HEAD + hh] = ps[m];
                adst[node * N_HEAD + hh] = pd[m];
            }
        }
    }
}

// Kernel 2: 4 nodes per wave, lane = g*16 + r.
// TA-address reduction: dst via ONE coalesced dword/lane (64 consecutive),
// adst via ONE float4 gather/lane (16 addrs/node vs 256 scalar), both
// redistributed through LDS (LDS pipe is idle). hp gather unchanged.
__global__ __launch_bounds__(256) void gat_agg(
    const int* __restrict__ dst, const uint4* __restrict__ hp,
    const float* __restrict__ asrc, const float* __restrict__ adst,
    const float* __restrict__ fc_b, const float* __restrict__ bias,
    float* __restrict__ out, int N)
{
    __shared__ int   dk_s[4][64];        // [wave][g*16+k]
    __shared__ float ad_s[4][4 * 68];    // [wave][g*68 + k*4 + c], pad->no conflicts

    int chunk = gridDim.x >> 3;
    int b  = blockIdx.x;
    int vb = (b & 7) * chunk + (b >> 3);
    int t = threadIdx.x;
    int wid = t >> 6, lane = t & 63;
    int g = lane >> 4, r = lane & 15;
    int wbase = vb * 16 + wid * 4;       // first node of this wave
    int node  = wbase + g;
    int nodec = node < N ? node : N - 1;
    int c = r >> 2;

    // 1 coalesced dst load per lane: edge (wbase*16 + lane), clamped tail
    int eidx = wbase * DEG + lane;
    int emax = N * DEG - 1;
    eidx = eidx < emax ? eidx : emax;
    int dval = dst[eidx];                 // = dst[node g][edge r] (when in range)
    dk_s[wid][lane] = dval;

    // 1 float4 adst gather per lane (node dval, all 4 heads)
    float4 ad4 = ((const float4*)adst)[dval];
    float* ads = &ad_s[wid][g * 68 + r * 4];
    ads[0] = ad4.x; ads[1] = ad4.y; ads[2] = ad4.z; ads[3] = ad4.w;

    __syncthreads();

    float as = asrc[(nodec << 2) + c];
    float bb = fc_b[0];

    // softmax over 16 edges for head c; adst values from LDS (conflict-free)
    float p[16];
    float mx = -1e30f;
    #pragma unroll
    for (int k = 0; k < 16; ++k) {
        float v = as + ad_s[wid][g * 68 + k * 4 + c] + bb;
        v = v > 0.f ? v : 0.2f * v;
        p[k] = v;
        mx = fmaxf(mx, v);
    }
    float s = 0.f;
    #pragma unroll
    for (int k = 0; k < 16; ++k) { p[k] = __expf(p[k] - mx); s += p[k]; }
    float inv = 1.f / s;

    // accumulate slice r over all 16 edges; dk from LDS broadcast
    float acc[8];
    #pragma unroll
    for (int j = 0; j < 8; ++j) acc[j] = 0.f;
    #pragma unroll
    for (int k = 0; k < 16; ++k) {
        int dkk = dk_s[wid][g * 16 + k];
        H8 v; v.u = hp[(dkk << 4) + r];
        float a = p[k];
        #pragma unroll
        for (int j = 0; j < 8; ++j) acc[j] = fmaf(a, __half2float(v.h[j]), acc[j]);
    }
    #pragma unroll
    for (int j = 0; j < 8; ++j) acc[j] *= inv;

    // head-mean across c (bits 2,3 of r)
    #pragma unroll
    for (int j = 0; j < 8; ++j) acc[j] += __shfl_xor(acc[j], 4, 64);
    #pragma unroll
    for (int j = 0; j < 8; ++j) acc[j] += __shfl_xor(acc[j], 8, 64);

    if (node < N && r < 4) {
        float4 b0 = ((const float4*)bias)[r * 2];
        float4 b1 = ((const float4*)bias)[r * 2 + 1];
        float4 o0, o1;
        o0.x = 0.25f * acc[0] + b0.x;
        o0.y = 0.25f * acc[1] + b0.y;
        o0.z = 0.25f * acc[2] + b0.z;
        o0.w = 0.25f * acc[3] + b0.w;
        o1.x = 0.25f * acc[4] + b1.x;
        o1.y = 0.25f * acc[5] + b1.y;
        o1.z = 0.25f * acc[6] + b1.z;
        o1.w = 0.25f * acc[7] + b1.w;
        ((float4*)out)[node * 8 + r * 2]     = o0;
        ((float4*)out)[node * 8 + r * 2 + 1] = o1;
    }
}

extern "C" void kernel_launch(void* const* d_in, const int* in_sizes, int n_in,
                              void* d_out, int out_size, void* d_ws, size_t ws_size,
                              hipStream_t stream) {
    const float* h    = (const float*)d_in[0];
    const int*   eidx = (const int*)  d_in[1];
    const float* w    = (const float*)d_in[2];
    const float* fc_w = (const float*)d_in[3];
    const float* fc_b = (const float*)d_in[4];
    const float* bias = (const float*)d_in[5];

    int N = in_sizes[0] / F_IN;
    int E = in_sizes[1] / 2;
    const int* dst = eidx + E;     // edge_index[1]

    ushort4* hp  = (ushort4*)d_ws;                     // N*32 ushort4 (fp16)
    float* asrc  = (float*)(hp + (size_t)N * 32);      // N*4
    float* adst  = asrc + (size_t)N * N_HEAD;          // N*4
    float* out   = (float*)d_out;

    int nbp    = (N + 31) / 32;
    int chunkp = (nbp + 7) / 8;
    gat_proj<<<8 * chunkp, 256, 0, stream>>>(h, w, fc_w, hp, asrc, adst, N);

    int nvb    = (N + 15) / 16;
    int chunka = (nvb + 7) / 8;
    gat_agg<<<8 * chunka, 256, 0, stream>>>(dst, (const uint4*)hp, asrc, adst,
                                            fc_b, bias, out, N);
}